// Round 18
// baseline (280.226 us; speedup 1.0000x reference)
//
#include <hip/hip_runtime.h>
#include <hip/hip_bf16.h>

#define BB 256
#define LL 200
#define CC 4
#define HH 128
#define G3 384
#define XPAD 168

typedef short bf16x8 __attribute__((ext_vector_type(8)));
typedef float f32x4 __attribute__((ext_vector_type(4)));

#define MFMA16(a, b, c) __builtin_amdgcn_mfma_f32_16x16x32_bf16((a), (b), (c), 0, 0, 0)

__device__ __forceinline__ short bf16_rne(float x) {
    union { float f; unsigned u; } v; v.f = x;
    unsigned r = v.u + 0x7FFFu + ((v.u >> 16) & 1u);
    return (short)(r >> 16);
}
__device__ __forceinline__ float rcp_(float x) { return __builtin_amdgcn_rcpf(x); }
__device__ __forceinline__ float sigm_(float x) { return rcp_(1.0f + __expf(-x)); }
__device__ __forceinline__ float tanhf_(float x) { return 2.0f * rcp_(1.0f + __expf(-2.0f * x)) - 1.0f; }

__device__ __forceinline__ unsigned cvtpk(float lo, float hi) {
    unsigned r;
    asm("v_cvt_pk_bf16_f32 %0, %1, %2" : "=v"(r) : "v"(lo), "v"(hi));
    return r;
}

// ---------------------------------------------------------------------------
// lengths from timeline_mask (bool-dtype detection, verified R1-R17)
// ---------------------------------------------------------------------------
__global__ void compute_lens_kernel(const unsigned char* __restrict__ mask8,
                                    int* __restrict__ lens) {
    __shared__ int bad;
    int b = threadIdx.x;
    if (b == 0) bad = 0;
    __syncthreads();
    int cnt8 = 0, prev = 0, mono = 1;
    for (int t = 0; t < LL; ++t) {
        int v = mask8[b * LL + t] ? 1 : 0;
        cnt8 += (v == 0);
        if (v < prev) mono = 0;
        prev = v;
    }
    if (!mono) atomicAdd(&bad, 1);
    __syncthreads();
    int len;
    if (bad == 0) {
        len = cnt8;
    } else {
        const int* m32 = (const int*)mask8;
        int c = 0;
        for (int t = 0; t < LL; ++t) c += (m32[b * LL + t] == 0);
        len = c;
    }
    if (len < 1) len = 1;
    if (len > LL) len = LL;
    lens[b] = len;
}

// ---------------------------------------------------------------------------
// weight split: bf16 hi for W_ih and W_hh
// ---------------------------------------------------------------------------
__global__ void wsplit_kernel(const float* __restrict__ Wih, const float* __restrict__ Whh,
                              short* __restrict__ wih_hi, short* __restrict__ whh_hi) {
    int i = blockIdx.x * 256 + threadIdx.x;   // 768 blocks -> 196608
    wih_hi[i] = bf16_rne(Wih[i]);
    whh_hi[i] = bf16_rne(Whh[i]);
}

// ---------------------------------------------------------------------------
// Producer/consumer specialized GRU. grid (16 bt x 4 c) = 64 WGs, 512 thr.
// Waves 0-3 = CONSUMERS: each owns 96 gate-cols (6 NT tiles): 24 rec MFMA +
//   gates(8 vals) + h/out writes. Waves 4-7 = PRODUCERS: compute
//   xp(si+1) = x.W_ih^T (+folded biases) into a shared f32 LDS buffer, plus
//   x staging. 1 consumer + 1 producer per SIMD -> producer work overlaps
//   consumer gates (m114 separate pipes).
// Two barriers/step with a SINGLE xp buffer (46KB LDS total):
//   {cons: hA+xp reads | prod: xs reads} B1
//   {cons: MFMA+gates+writes | prod: MFMA+xp writes+stage} B2
// Numerics identical to R17 (xp f32 through LDS): absmax must be 0.005859375.
// ---------------------------------------------------------------------------
__global__ __launch_bounds__(512, 2) void gru_fused_kernel(
    const float* __restrict__ seqs,    // (B,L,C,H)
    const int*   __restrict__ lens,    // (B,)
    const short* __restrict__ wih_hi,  // (C,384,128) bf16
    const short* __restrict__ whh_hi,  // (C,384,128) bf16
    const float* __restrict__ b_ih,    // (C,384)
    const float* __restrict__ b_hh,    // (C,384)
    float*       __restrict__ out)     // (C,B,L,H)
{
    const int bt = blockIdx.x;             // 0..15
    const int c  = blockIdx.y;             // 0..3
    const int bbase = bt * 16;
    const int tid = threadIdx.x;           // 0..511
    const int w = tid >> 6;                // wave 0..7
    const int l = tid & 63;
    const int l15 = l & 15, g = l >> 4;
    const int role = w >> 2;               // 0 = consumer, 1 = producer
    const int wq = w & 3;                  // col-quarter [32wq, 32wq+32)

    __shared__ __align__(16) short hA[2][16][XPAD];   // 10.5 KB bf16 h
    __shared__ __align__(16) short xs[2][16][XPAD];   // 10.5 KB bf16 x
    __shared__ __align__(16) float xp[G3][16];        // 24.6 KB f32 xp (single)

    // ---- weights: consumer = W_hh tiles, producer = W_ih tiles ----
    // NT(q) = gate*8 + 2*wq + cp   (gate = q>>1, cp = q&1)
    bf16x8 W[6][4];
    {
        const short* wsrc = role ? wih_hi : whh_hi;
        #pragma unroll
        for (int q = 0; q < 6; ++q) {
            const int NT = (q >> 1) * 8 + 2 * wq + (q & 1);
            #pragma unroll
            for (int ks = 0; ks < 4; ++ks) {
                size_t off = (size_t)(c * G3 + NT * 16 + l15) * HH + ks * 32 + g * 8;
                W[q][ks] = *(const bf16x8*)(wsrc + off);
            }
        }
    }
    #pragma unroll
    for (int q = 0; q < 6; ++q)
        asm volatile("" : "+a"(W[q][0]), "+a"(W[q][1]), "+a"(W[q][2]), "+a"(W[q][3]));

    const int colA = 32 * wq + l15;
    const int colB = colA + 16;

    // ---- role-specific C-init biases ----
    f32x4 ci[6];
    if (role) {
        float bRa = b_hh[c * G3 + colA]       + b_ih[c * G3 + colA];
        float bRb = b_hh[c * G3 + colB]       + b_ih[c * G3 + colB];
        float bZa = b_hh[c * G3 + 128 + colA] + b_ih[c * G3 + 128 + colA];
        float bZb = b_hh[c * G3 + 128 + colB] + b_ih[c * G3 + 128 + colB];
        float bNa = b_ih[c * G3 + 256 + colA];
        float bNb = b_ih[c * G3 + 256 + colB];
        ci[0] = (f32x4){bRa, bRa, bRa, bRa};
        ci[1] = (f32x4){bRb, bRb, bRb, bRb};
        ci[2] = (f32x4){bZa, bZa, bZa, bZa};
        ci[3] = (f32x4){bZb, bZb, bZb, bZb};
        ci[4] = (f32x4){bNa, bNa, bNa, bNa};
        ci[5] = (f32x4){bNb, bNb, bNb, bNb};
    } else {
        float bHa = b_hh[c * G3 + 256 + colA];
        float bHb = b_hh[c * G3 + 256 + colB];
        ci[0] = (f32x4){0.f, 0.f, 0.f, 0.f};
        ci[1] = (f32x4){0.f, 0.f, 0.f, 0.f};
        ci[2] = (f32x4){0.f, 0.f, 0.f, 0.f};
        ci[3] = (f32x4){0.f, 0.f, 0.f, 0.f};
        ci[4] = (f32x4){bHa, bHa, bHa, bHa};
        ci[5] = (f32x4){bHb, bHb, bHb, bHb};
    }

    // ---- consumer per-lane output state ----
    int lenr[4], tcur[4];
    float hold[2][4];
    if (!role) {
        #pragma unroll
        for (int r = 0; r < 4; ++r) {
            lenr[r] = lens[bbase + g * 4 + r];
            tcur[r] = LL - lenr[r];
        }
        #pragma unroll
        for (int cp = 0; cp < 2; ++cp)
            #pragma unroll
            for (int r = 0; r < 4; ++r) hold[cp][r] = 0.f;
    }

    // ---- producer stager state (256 threads: 16 rows x 16 thr x 8 floats) ----
    const int ptid = tid & 255;
    const int prow = ptid >> 4;
    const int pk0  = (ptid & 15) * 8;
    const float* srow = nullptr;
    float4 xra, xrb;
    int txs = 0;
    if (role) {
        const int lenS = lens[bbase + prow];
        srow = seqs + ((size_t)(bbase + prow) * LL * CC + c) * HH + pk0;
        int t0 = LL - lenS;
        int t1 = t0 + 1; if (t1 >= LL) t1 -= LL;
        float4 a0 = *(const float4*)(srow + (size_t)t0 * (CC * HH));
        float4 a1 = *(const float4*)(srow + (size_t)t0 * (CC * HH) + 4);
        float4 b0 = *(const float4*)(srow + (size_t)t1 * (CC * HH));
        float4 b1 = *(const float4*)(srow + (size_t)t1 * (CC * HH) + 4);
        *(uint4*)&xs[0][prow][pk0] = make_uint4(cvtpk(a0.x, a0.y), cvtpk(a0.z, a0.w),
                                                cvtpk(a1.x, a1.y), cvtpk(a1.z, a1.w));
        *(uint4*)&xs[1][prow][pk0] = make_uint4(cvtpk(b0.x, b0.y), cvtpk(b0.z, b0.w),
                                                cvtpk(b1.x, b1.y), cvtpk(b1.z, b1.w));
        txs = t1 + 1; if (txs >= LL) txs -= LL;            // t of s=2
        xra = *(const float4*)(srow + (size_t)txs * (CC * HH));
        xrb = *(const float4*)(srow + (size_t)txs * (CC * HH) + 4);
        txs = (txs + 1 == LL) ? 0 : txs + 1;
    }

    // ---- zero hA[0] ----
    for (int i = tid; i < 16 * XPAD / 2; i += 512) ((int*)hA[0])[i] = 0;
    __syncthreads();

    // ---- prologue: producers compute xp(0) from xs[0] ----
    if (role) {
        bf16x8 xh[4];
        #pragma unroll
        for (int ks = 0; ks < 4; ++ks)
            xh[ks] = *(const bf16x8*)&xs[0][l15][ks * 32 + g * 8];
        f32x4 xn[6];
        #pragma unroll
        for (int q = 0; q < 6; ++q) xn[q] = ci[q];
        #pragma unroll
        for (int ks = 0; ks < 4; ++ks)
            #pragma unroll
            for (int q = 0; q < 6; ++q)
                xn[q] = MFMA16(xh[ks], W[q][ks], xn[q]);
        #pragma unroll
        for (int q = 0; q < 6; ++q) {
            const int NT = (q >> 1) * 8 + 2 * wq + (q & 1);
            *(f32x4*)&xp[NT * 16 + l15][g * 4] = xn[q];
        }
    }
    __syncthreads();

    // =======================  main loop  =======================
    for (int si = 0; si < LL; ++si) {
        const int hb = si & 1, hn = hb ^ 1;

        bf16x8 ah[4], xh[4];
        f32x4 xpv[6];
        if (!role) {
            // consumer: read h frags + xp values (single buffer, pre-B1)
            #pragma unroll
            for (int ks = 0; ks < 4; ++ks)
                ah[ks] = *(const bf16x8*)&hA[hb][l15][ks * 32 + g * 8];
            #pragma unroll
            for (int q = 0; q < 6; ++q) {
                const int NT = (q >> 1) * 8 + 2 * wq + (q & 1);
                xpv[q] = *(const f32x4*)&xp[NT * 16 + l15][g * 4];
            }
        } else {
            // producer: read x(si+1) frags
            #pragma unroll
            for (int ks = 0; ks < 4; ++ks)
                xh[ks] = *(const bf16x8*)&xs[hn][l15][ks * 32 + g * 8];
        }
        asm volatile("s_waitcnt lgkmcnt(0)" ::: "memory");
        __builtin_amdgcn_s_barrier();                     // B1: reads done
        __builtin_amdgcn_sched_barrier(0);

        if (!role) {
            // rec MFMAs: 6 independent depth-4 chains
            f32x4 racc[6];
            #pragma unroll
            for (int q = 0; q < 6; ++q) racc[q] = ci[q];
            #pragma unroll
            for (int ks = 0; ks < 4; ++ks)
                #pragma unroll
                for (int q = 0; q < 6; ++q)
                    racc[q] = MFMA16(ah[ks], W[q][ks], racc[q]);

            // gates: 8 values (2 cols x 4 rows)
            float hnew[2][4];
            #pragma unroll
            for (int cp = 0; cp < 2; ++cp)
                #pragma unroll
                for (int r = 0; r < 4; ++r) {
                    float gr = sigm_(racc[0 + cp][r] + xpv[0 + cp][r]);
                    float gz = sigm_(racc[2 + cp][r] + xpv[2 + cp][r]);
                    float gn = tanhf_(xpv[4 + cp][r] + gr * racc[4 + cp][r]);
                    float hv = gn + gz * (hold[cp][r] - gn);
                    hnew[cp][r] = hv;
                    hold[cp][r] = hv;
                }

            // h -> bf16 -> hA[hn]
            {
                unsigned pA01 = cvtpk(hold[0][0], hold[0][1]);
                unsigned pA23 = cvtpk(hold[0][2], hold[0][3]);
                unsigned pB01 = cvtpk(hold[1][0], hold[1][1]);
                unsigned pB23 = cvtpk(hold[1][2], hold[1][3]);
                hA[hn][g * 4 + 0][colA] = (short)(pA01 & 0xffffu);
                hA[hn][g * 4 + 1][colA] = (short)(pA01 >> 16);
                hA[hn][g * 4 + 2][colA] = (short)(pA23 & 0xffffu);
                hA[hn][g * 4 + 3][colA] = (short)(pA23 >> 16);
                hA[hn][g * 4 + 0][colB] = (short)(pB01 & 0xffffu);
                hA[hn][g * 4 + 1][colB] = (short)(pB01 >> 16);
                hA[hn][g * 4 + 2][colB] = (short)(pB23 & 0xffffu);
                hA[hn][g * 4 + 3][colB] = (short)(pB23 >> 16);
            }

            // out stores (2 cols x 4 rows)
            #pragma unroll
            for (int r = 0; r < 4; ++r) {
                int t = tcur[r];
                int valid = t < lenr[r];
                float* op = &out[((size_t)(c * BB + bbase + g * 4 + r) * LL + t) * HH + colA];
                op[0]  = valid ? hnew[0][r] : 0.0f;
                op[16] = valid ? hnew[1][r] : 0.0f;
                tcur[r] = (t + 1 == LL) ? 0 : t + 1;
            }
        } else {
            // producer: xp(si+1) MFMAs -> xp buffer (post-B1 write is safe)
            f32x4 xn[6];
            #pragma unroll
            for (int q = 0; q < 6; ++q) xn[q] = ci[q];
            #pragma unroll
            for (int ks = 0; ks < 4; ++ks)
                #pragma unroll
                for (int q = 0; q < 6; ++q)
                    xn[q] = MFMA16(xh[ks], W[q][ks], xn[q]);
            #pragma unroll
            for (int q = 0; q < 6; ++q) {
                const int NT = (q >> 1) * 8 + 2 * wq + (q & 1);
                *(f32x4*)&xp[NT * 16 + l15][g * 4] = xn[q];
            }
            // stage x(si+2) -> xs[hb]; issue x(si+3)
            *(uint4*)&xs[hb][prow][pk0] = make_uint4(cvtpk(xra.x, xra.y), cvtpk(xra.z, xra.w),
                                                     cvtpk(xrb.x, xrb.y), cvtpk(xrb.z, xrb.w));
            xra = *(const float4*)(srow + (size_t)txs * (CC * HH));
            xrb = *(const float4*)(srow + (size_t)txs * (CC * HH) + 4);
            txs = (txs + 1 == LL) ? 0 : txs + 1;
        }
        asm volatile("s_waitcnt lgkmcnt(0)" ::: "memory");
        __builtin_amdgcn_s_barrier();                     // B2: writes done
        __builtin_amdgcn_sched_barrier(0);
        asm volatile("" ::: "memory");
    }
}

extern "C" void kernel_launch(void* const* d_in, const int* in_sizes, int n_in,
                              void* d_out, int out_size, void* d_ws, size_t ws_size,
                              hipStream_t stream) {
    const float* seqs  = (const float*)d_in[0];
    const unsigned char* tmask = (const unsigned char*)d_in[1];
    // d_in[2] = attention_mask (all false, unused)
    const float* W_ih  = (const float*)d_in[3];
    const float* W_hh  = (const float*)d_in[4];
    const float* b_ih  = (const float*)d_in[5];
    const float* b_hh  = (const float*)d_in[6];
    float* out = (float*)d_out;

    char* ws = (char*)d_ws;
    int*   lens   = (int*)(ws);                       // 1 KB
    short* wih_hi = (short*)(ws + 1024);              // 384 KB
    short* whh_hi = (short*)(ws + 1024 + 393216);     // 384 KB

    compute_lens_kernel<<<1, BB, 0, stream>>>(tmask, lens);
    wsplit_kernel<<<768, 256, 0, stream>>>(W_ih, W_hh, wih_hi, whh_hi);

    gru_fused_kernel<<<dim3(16, CC), 512, 0, stream>>>(
        seqs, lens, wih_hi, whh_hi, b_ih, b_hh, out);
}

// Round 19
// 203.825 us; speedup vs baseline: 1.3748x; 1.3748x over previous
//
#include <hip/hip_runtime.h>
#include <hip/hip_bf16.h>

#define BB 256
#define LL 200
#define CC 4
#define HH 128
#define G3 384

typedef short bf16x8 __attribute__((ext_vector_type(8)));
typedef float f32x4 __attribute__((ext_vector_type(4)));

#define MFMA16(a, b, c) __builtin_amdgcn_mfma_f32_16x16x32_bf16((a), (b), (c), 0, 0, 0)

__device__ __forceinline__ short bf16_rne(float x) {
    union { float f; unsigned u; } v; v.f = x;
    unsigned r = v.u + 0x7FFFu + ((v.u >> 16) & 1u);
    return (short)(r >> 16);
}
__device__ __forceinline__ float rcp_(float x) { return __builtin_amdgcn_rcpf(x); }
__device__ __forceinline__ float sigm_(float x) { return rcp_(1.0f + __expf(-x)); }
__device__ __forceinline__ float tanhf_(float x) { return 2.0f * rcp_(1.0f + __expf(-2.0f * x)) - 1.0f; }

__device__ __forceinline__ unsigned cvtpk(float lo, float hi) {
    unsigned r;
    asm("v_cvt_pk_bf16_f32 %0, %1, %2" : "=v"(r) : "v"(lo), "v"(hi));
    return r;
}
__device__ __forceinline__ uint2 pack4(float4 v) {
    uint2 p;
    p.x = cvtpk(v.x, v.y);
    p.y = cvtpk(v.z, v.w);
    return p;
}

// ---------------------------------------------------------------------------
// lengths from timeline_mask (bool-dtype detection, verified R1-R18)
// ---------------------------------------------------------------------------
__global__ void compute_lens_kernel(const unsigned char* __restrict__ mask8,
                                    int* __restrict__ lens) {
    __shared__ int bad;
    int b = threadIdx.x;
    if (b == 0) bad = 0;
    __syncthreads();
    int cnt8 = 0, prev = 0, mono = 1;
    for (int t = 0; t < LL; ++t) {
        int v = mask8[b * LL + t] ? 1 : 0;
        cnt8 += (v == 0);
        if (v < prev) mono = 0;
        prev = v;
    }
    if (!mono) atomicAdd(&bad, 1);
    __syncthreads();
    int len;
    if (bad == 0) {
        len = cnt8;
    } else {
        const int* m32 = (const int*)mask8;
        int c = 0;
        for (int t = 0; t < LL; ++t) c += (m32[b * LL + t] == 0);
        len = c;
    }
    if (len < 1) len = 1;
    if (len > LL) len = LL;
    lens[b] = len;
}

// ---------------------------------------------------------------------------
// weight split: bf16 hi for W_ih and W_hh
// ---------------------------------------------------------------------------
__global__ void wsplit_kernel(const float* __restrict__ Wih, const float* __restrict__ Whh,
                              short* __restrict__ wih_hi, short* __restrict__ whh_hi) {
    int i = blockIdx.x * 256 + threadIdx.x;   // 768 blocks -> 196608
    wih_hi[i] = bf16_rne(Wih[i]);
    whh_hi[i] = bf16_rne(Whh[i]);
}

// ---------------------------------------------------------------------------
// Fused GRU: grid (16 bt x 4 c) = 64 WGs, 512 thr = 8 waves = 2 waves/SIMD.
// R19 = R17 (proven 203.6us) with:
//  - AGPR pins REMOVED: demand = 96 weight + ~116 working = 212 <= 256-cap
//    at 2 waves/SIMD; hypothesis: "+a" pins cost per-MFMA v_accvgpr_read
//    copies (~96 VALU/step) explaining the VALU gap. Sentinels: VGPR_Count
//    ~190-250 good; ~116 + FETCH jump = remat -> revert.
//  - FRAGMENT-LINEAR hA/xs: [buf][ks][lane*8] (lane-sequential 1024B/ks =
//    structural b128 floor, m97 pattern). R15/R17 strides were both 8-way
//    (conflict counter bit-identical). Writer-side scatter per derivation:
//    h(row,col) -> [col>>5][(((col>>3)&3)*16+row)*8 + (col&7)].
//  - pointer-walk out stores + stager loads (no per-step 64b addr math).
// Numerics identical to R17: absmax must be exactly 0.005859375.
// ---------------------------------------------------------------------------
__global__ __launch_bounds__(512, 2) void gru_fused_kernel(
    const float* __restrict__ seqs,    // (B,L,C,H)
    const int*   __restrict__ lens,    // (B,)
    const short* __restrict__ wih_hi,  // (C,384,128) bf16
    const short* __restrict__ whh_hi,  // (C,384,128) bf16
    const float* __restrict__ b_ih,    // (C,384)
    const float* __restrict__ b_hh,    // (C,384)
    float*       __restrict__ out)     // (C,B,L,H)
{
    const int bt = blockIdx.x;             // 0..15
    const int c  = blockIdx.y;             // 0..3
    const int bbase = bt * 16;
    const int tid = threadIdx.x;           // 0..511
    const int w = tid >> 6;                // wave 0..7
    const int l = tid & 63;
    const int l15 = l & 15, g = l >> 4;    // A-row = l15, k-group = g

    // fragment-linear: [buf][ks][lane*8 + j]  (4 KB per buf)
    __shared__ __align__(16) short hA[2][4][512];
    __shared__ __align__(16) short xs[2][4][512];

    // ---- weight fragments (plain VGPR residency; no pins) ----
    bf16x8 BH[3][4], WI[3][4];
    #pragma unroll
    for (int q = 0; q < 3; ++q) {
        const int NT = q * 8 + w;
        #pragma unroll
        for (int ks = 0; ks < 4; ++ks) {
            size_t off = (size_t)(c * G3 + NT * 16 + l15) * HH + ks * 32 + g * 8;
            BH[q][ks] = *(const bf16x8*)(whh_hi + off);
            WI[q][ks] = *(const bf16x8*)(wih_hi + off);
        }
    }

    // ---- h writer scatter constants: col0 = w*16 + l15 ----
    const int col0 = w * 16 + l15;
    const int ksw = w >> 1;                         // col0 >> 5
    const int hwbase = (((w & 1) * 2 + (l15 >> 3)) * 16 + g * 4) * 8 + (l15 & 7);

    // ---- stager: thread stages batch row tid>>5, 4 floats (k0s..k0s+3) ----
    const int bsl = tid >> 5;               // 0..15
    const int k0s = (tid & 31) * 4;         // 0..124
    const int ksx = k0s >> 5;
    const int xwbase = ((((k0s >> 3) & 3) * 16 + bsl) * 8 + (k0s & 7));
    const int lenS = lens[bbase + bsl];
    const float* srow0 = seqs + ((size_t)(bbase + bsl) * LL * CC + c) * HH + k0s;
    int ts0 = LL - lenS;
    int ts1 = ts0 + 1; if (ts1 >= LL) ts1 -= LL;
    float4 xr0 = *(const float4*)(srow0 + (size_t)ts0 * (CC * HH));
    float4 xr1 = *(const float4*)(srow0 + (size_t)ts1 * (CC * HH));
    int txs = ts1 + 1; if (txs >= LL) txs -= LL;   // t for s=2
    const float* xptr = srow0 + (size_t)txs * (CC * HH);
    const ptrdiff_t xstep = CC * HH;
    const ptrdiff_t xwrap = (ptrdiff_t)(LL - 1) * CC * HH;

    // ---- biases -> persistent C-init vectors ----
    const float bRs = b_hh[c * G3 + col0]       + b_ih[c * G3 + col0];
    const float bZs = b_hh[c * G3 + 128 + col0] + b_ih[c * G3 + 128 + col0];
    const float bHN = b_hh[c * G3 + 256 + col0];
    const float bIN = b_ih[c * G3 + 256 + col0];
    const f32x4 cZZ  = (f32x4){0.f, 0.f, 0.f, 0.f};
    const f32x4 cHN4 = (f32x4){bHN, bHN, bHN, bHN};
    const f32x4 cR4  = (f32x4){bRs, bRs, bRs, bRs};
    const f32x4 cZ4  = (f32x4){bZs, bZs, bZs, bZs};
    const f32x4 cN4  = (f32x4){bIN, bIN, bIN, bIN};

    // ---- per-lane output rows: batches bbase + g*4 + r (pointer-walk) ----
    int lenr[4], tcur[4];
    float* optr[4];
    #pragma unroll
    for (int r = 0; r < 4; ++r) {
        lenr[r] = lens[bbase + g * 4 + r];
        tcur[r] = LL - lenr[r];
        optr[r] = out + ((size_t)(c * BB + bbase + g * 4 + r) * LL + tcur[r]) * HH + col0;
    }
    const ptrdiff_t owrap = (ptrdiff_t)(LL - 1) * HH;
    float hold[4] = { 0.f, 0.f, 0.f, 0.f };

    // ---- zero h buffer 0 (4*512 shorts = 1024 dwords) ----
    for (int i = tid; i < 1024; i += 512) ((int*)hA[0])[i] = 0;

    // ---- stage x(0)->xs[0], x(1)->xs[1] ----
    *(uint2*)&xs[0][ksx][xwbase] = pack4(xr0);
    *(uint2*)&xs[1][ksx][xwbase] = pack4(xr1);
    __syncthreads();

    // ---- xacc(0) from xs[0] (C-init peeled) ----
    f32x4 xacc[3];
    {
        bf16x8 xh0 = *(const bf16x8*)&xs[0][0][l * 8];
        xacc[0] = MFMA16(xh0, WI[0][0], cR4);
        xacc[1] = MFMA16(xh0, WI[1][0], cZ4);
        xacc[2] = MFMA16(xh0, WI[2][0], cN4);
        #pragma unroll
        for (int ks = 1; ks < 4; ++ks) {
            bf16x8 xh = *(const bf16x8*)&xs[0][ks][l * 8];
            #pragma unroll
            for (int q = 0; q < 3; ++q)
                xacc[q] = MFMA16(xh, WI[q][ks], xacc[q]);
        }
    }
    // issue x(2)
    float4 xraw = *(const float4*)xptr;
    txs = (txs + 1 == LL) ? 0 : txs + 1;
    xptr = (txs == 0) ? xptr - xwrap : xptr + xstep;

    __syncthreads();   // protect xs[0] from step-0 overwrite

    // =======================  main loop  =======================
    for (int si = 0; si < LL; ++si) {
        const int hb = si & 1, hn = hb ^ 1;

        // 1. rec MFMAs: 12 total, C-init peeled (conflict-free frag reads)
        f32x4 racc[3];
        {
            bf16x8 ah0 = *(const bf16x8*)&hA[hb][0][l * 8];
            racc[0] = MFMA16(ah0, BH[0][0], cZZ);
            racc[1] = MFMA16(ah0, BH[1][0], cZZ);
            racc[2] = MFMA16(ah0, BH[2][0], cHN4);
            #pragma unroll
            for (int ks = 1; ks < 4; ++ks) {
                bf16x8 ah = *(const bf16x8*)&hA[hb][ks][l * 8];
                #pragma unroll
                for (int q = 0; q < 3; ++q) racc[q] = MFMA16(ah, BH[q][ks], racc[q]);
            }
        }

        // 2. gates (xacc = xp(si), biases folded)
        float hnew[4];
        #pragma unroll
        for (int r = 0; r < 4; ++r) {
            float gr = sigm_(racc[0][r] + xacc[0][r]);
            float gz = sigm_(racc[1][r] + xacc[1][r]);
            float gn = tanhf_(xacc[2][r] + gr * racc[2][r]);
            float hv = gn + gz * (hold[r] - gn);
            hnew[r] = hv;
            hold[r] = hv;
        }

        // 3. h -> bf16 -> hA[hn] frag-scatter (writes drain under xproj)
        {
            unsigned pk01 = cvtpk(hold[0], hold[1]);
            unsigned pk23 = cvtpk(hold[2], hold[3]);
            hA[hn][ksw][hwbase]      = (short)(pk01 & 0xffffu);
            hA[hn][ksw][hwbase + 8]  = (short)(pk01 >> 16);
            hA[hn][ksw][hwbase + 16] = (short)(pk23 & 0xffffu);
            hA[hn][ksw][hwbase + 24] = (short)(pk23 >> 16);
        }

        // 4. out stores (pointer-walk, zero-masked; fire-and-forget)
        #pragma unroll
        for (int r = 0; r < 4; ++r) {
            int t = tcur[r];
            *optr[r] = (t < lenr[r]) ? hnew[r] : 0.0f;
            int wrapped = (t + 1 == LL);
            tcur[r] = wrapped ? 0 : t + 1;
            optr[r] = wrapped ? optr[r] - owrap : optr[r] + HH;
        }

        // 5. xproj for si+1 (off-chain; C-init peeled)
        {
            bf16x8 xh0 = *(const bf16x8*)&xs[hn][0][l * 8];
            xacc[0] = MFMA16(xh0, WI[0][0], cR4);
            xacc[1] = MFMA16(xh0, WI[1][0], cZ4);
            xacc[2] = MFMA16(xh0, WI[2][0], cN4);
            #pragma unroll
            for (int ks = 1; ks < 4; ++ks) {
                bf16x8 xh = *(const bf16x8*)&xs[hn][ks][l * 8];
                #pragma unroll
                for (int q = 0; q < 3; ++q)
                    xacc[q] = MFMA16(xh, WI[q][ks], xacc[q]);
            }
        }

        // 6. stage x(si+2) -> xs[hb]; 7. issue x(si+3) (pointer-walk)
        *(uint2*)&xs[hb][ksx][xwbase] = pack4(xraw);
        xraw = *(const float4*)xptr;
        txs = (txs + 1 == LL) ? 0 : txs + 1;
        xptr = (txs == 0) ? xptr - xwrap : xptr + xstep;

        // 8. lgkm-only drain + raw barrier (vmem ops stay in flight)
        asm volatile("s_waitcnt lgkmcnt(0)" ::: "memory");
        __builtin_amdgcn_s_barrier();
        __builtin_amdgcn_sched_barrier(0);
        asm volatile("" ::: "memory");
    }
}

extern "C" void kernel_launch(void* const* d_in, const int* in_sizes, int n_in,
                              void* d_out, int out_size, void* d_ws, size_t ws_size,
                              hipStream_t stream) {
    const float* seqs  = (const float*)d_in[0];
    const unsigned char* tmask = (const unsigned char*)d_in[1];
    // d_in[2] = attention_mask (all false, unused)
    const float* W_ih  = (const float*)d_in[3];
    const float* W_hh  = (const float*)d_in[4];
    const float* b_ih  = (const float*)d_in[5];
    const float* b_hh  = (const float*)d_in[6];
    float* out = (float*)d_out;

    char* ws = (char*)d_ws;
    int*   lens   = (int*)(ws);                       // 1 KB
    short* wih_hi = (short*)(ws + 1024);              // 384 KB
    short* whh_hi = (short*)(ws + 1024 + 393216);     // 384 KB

    compute_lens_kernel<<<1, BB, 0, stream>>>(tmask, lens);
    wsplit_kernel<<<768, 256, 0, stream>>>(W_ih, W_hh, wih_hi, whh_hi);

    gru_fused_kernel<<<dim3(16, CC), 512, 0, stream>>>(
        seqs, lens, wih_hi, whh_hi, b_ih, b_hh, out);
}

// Round 20
// 202.671 us; speedup vs baseline: 1.3827x; 1.0057x over previous
//
#include <hip/hip_runtime.h>
#include <hip/hip_bf16.h>

#define BB 256
#define LL 200
#define CC 4
#define HH 128
#define G3 384

typedef short bf16x8 __attribute__((ext_vector_type(8)));
typedef float f32x4 __attribute__((ext_vector_type(4)));

#define MFMA16(a, b, c) __builtin_amdgcn_mfma_f32_16x16x32_bf16((a), (b), (c), 0, 0, 0)

__device__ __forceinline__ short bf16_rne(float x) {
    union { float f; unsigned u; } v; v.f = x;
    unsigned r = v.u + 0x7FFFu + ((v.u >> 16) & 1u);
    return (short)(r >> 16);
}
__device__ __forceinline__ float rcp_(float x) { return __builtin_amdgcn_rcpf(x); }
__device__ __forceinline__ float sigm_(float x) { return rcp_(1.0f + __expf(-x)); }
__device__ __forceinline__ float tanhf_(float x) { return 2.0f * rcp_(1.0f + __expf(-2.0f * x)) - 1.0f; }

__device__ __forceinline__ unsigned cvtpk(float lo, float hi) {
    unsigned r;
    asm("v_cvt_pk_bf16_f32 %0, %1, %2" : "=v"(r) : "v"(lo), "v"(hi));
    return r;
}
__device__ __forceinline__ uint2 pack4(float4 v) {
    uint2 p;
    p.x = cvtpk(v.x, v.y);
    p.y = cvtpk(v.z, v.w);
    return p;
}

// ---------------------------------------------------------------------------
// lengths from timeline_mask (bool-dtype detection, verified R1-R19)
// ---------------------------------------------------------------------------
__global__ void compute_lens_kernel(const unsigned char* __restrict__ mask8,
                                    int* __restrict__ lens) {
    __shared__ int bad;
    int b = threadIdx.x;
    if (b == 0) bad = 0;
    __syncthreads();
    int cnt8 = 0, prev = 0, mono = 1;
    for (int t = 0; t < LL; ++t) {
        int v = mask8[b * LL + t] ? 1 : 0;
        cnt8 += (v == 0);
        if (v < prev) mono = 0;
        prev = v;
    }
    if (!mono) atomicAdd(&bad, 1);
    __syncthreads();
    int len;
    if (bad == 0) {
        len = cnt8;
    } else {
        const int* m32 = (const int*)mask8;
        int c = 0;
        for (int t = 0; t < LL; ++t) c += (m32[b * LL + t] == 0);
        len = c;
    }
    if (len < 1) len = 1;
    if (len > LL) len = LL;
    lens[b] = len;
}

// ---------------------------------------------------------------------------
// weight split: bf16 hi for W_ih and W_hh
// ---------------------------------------------------------------------------
__global__ void wsplit_kernel(const float* __restrict__ Wih, const float* __restrict__ Whh,
                              short* __restrict__ wih_hi, short* __restrict__ whh_hi) {
    int i = blockIdx.x * 256 + threadIdx.x;   // 768 blocks -> 196608
    wih_hi[i] = bf16_rne(Wih[i]);
    whh_hi[i] = bf16_rne(Whh[i]);
}

// ---------------------------------------------------------------------------
// Fused GRU: grid (16 bt x 4 c) = 64 WGs, 512 thr = 8 waves = 2 waves/SIMD.
// R20 = R19 (203.8us) with the step loop UNROLLED BY 2 (LL=200 even):
//  - hb/hn become compile-time per body -> all 16+ LDS accesses fold to one
//    base VGPR + offset: immediates (24KB block < 64KB imm range), deleting
//    per-step address recompute + dynamic-index selects (~40-60 VALU/step).
//  - sync structure per half-body unchanged (lgkm drain + raw barrier +
//    sched_barrier) - proven race-free lineage.
// Numerics identical: absmax must be exactly 0.005859375.
// ---------------------------------------------------------------------------
__global__ __launch_bounds__(512, 2) void gru_fused_kernel(
    const float* __restrict__ seqs,    // (B,L,C,H)
    const int*   __restrict__ lens,    // (B,)
    const short* __restrict__ wih_hi,  // (C,384,128) bf16
    const short* __restrict__ whh_hi,  // (C,384,128) bf16
    const float* __restrict__ b_ih,    // (C,384)
    const float* __restrict__ b_hh,    // (C,384)
    float*       __restrict__ out)     // (C,B,L,H)
{
    const int bt = blockIdx.x;             // 0..15
    const int c  = blockIdx.y;             // 0..3
    const int bbase = bt * 16;
    const int tid = threadIdx.x;           // 0..511
    const int w = tid >> 6;                // wave 0..7
    const int l = tid & 63;
    const int l15 = l & 15, g = l >> 4;    // A-row = l15, k-group = g

    // fragment-linear: [buf][ks][lane*8 + j]  (4 KB per buf)
    __shared__ __align__(16) short hA[2][4][512];
    __shared__ __align__(16) short xs[2][4][512];

    // ---- weight fragments ----
    bf16x8 BH[3][4], WI[3][4];
    #pragma unroll
    for (int q = 0; q < 3; ++q) {
        const int NT = q * 8 + w;
        #pragma unroll
        for (int ks = 0; ks < 4; ++ks) {
            size_t off = (size_t)(c * G3 + NT * 16 + l15) * HH + ks * 32 + g * 8;
            BH[q][ks] = *(const bf16x8*)(whh_hi + off);
            WI[q][ks] = *(const bf16x8*)(wih_hi + off);
        }
    }

    // ---- h writer scatter constants: col0 = w*16 + l15 ----
    const int col0 = w * 16 + l15;
    const int ksw = w >> 1;
    const int hwbase = (((w & 1) * 2 + (l15 >> 3)) * 16 + g * 4) * 8 + (l15 & 7);

    // ---- stager constants ----
    const int bsl = tid >> 5;               // 0..15
    const int k0s = (tid & 31) * 4;         // 0..124
    const int ksx = k0s >> 5;
    const int xwbase = ((((k0s >> 3) & 3) * 16 + bsl) * 8 + (k0s & 7));
    const int lenS = lens[bbase + bsl];
    const float* srow0 = seqs + ((size_t)(bbase + bsl) * LL * CC + c) * HH + k0s;
    int ts0 = LL - lenS;
    int ts1 = ts0 + 1; if (ts1 >= LL) ts1 -= LL;
    float4 xr0 = *(const float4*)(srow0 + (size_t)ts0 * (CC * HH));
    float4 xr1 = *(const float4*)(srow0 + (size_t)ts1 * (CC * HH));
    int txs = ts1 + 1; if (txs >= LL) txs -= LL;   // t for s=2
    const float* xptr = srow0 + (size_t)txs * (CC * HH);
    const ptrdiff_t xstep = CC * HH;
    const ptrdiff_t xwrap = (ptrdiff_t)(LL - 1) * CC * HH;

    // ---- biases -> persistent C-init vectors ----
    const float bRs = b_hh[c * G3 + col0]       + b_ih[c * G3 + col0];
    const float bZs = b_hh[c * G3 + 128 + col0] + b_ih[c * G3 + 128 + col0];
    const float bHN = b_hh[c * G3 + 256 + col0];
    const float bIN = b_ih[c * G3 + 256 + col0];
    const f32x4 cZZ  = (f32x4){0.f, 0.f, 0.f, 0.f};
    const f32x4 cHN4 = (f32x4){bHN, bHN, bHN, bHN};
    const f32x4 cR4  = (f32x4){bRs, bRs, bRs, bRs};
    const f32x4 cZ4  = (f32x4){bZs, bZs, bZs, bZs};
    const f32x4 cN4  = (f32x4){bIN, bIN, bIN, bIN};

    // ---- per-lane output rows (pointer-walk) ----
    int lenr[4], tcur[4];
    float* optr[4];
    #pragma unroll
    for (int r = 0; r < 4; ++r) {
        lenr[r] = lens[bbase + g * 4 + r];
        tcur[r] = LL - lenr[r];
        optr[r] = out + ((size_t)(c * BB + bbase + g * 4 + r) * LL + tcur[r]) * HH + col0;
    }
    const ptrdiff_t owrap = (ptrdiff_t)(LL - 1) * HH;
    float hold[4] = { 0.f, 0.f, 0.f, 0.f };

    // ---- zero h buffer 0 ----
    for (int i = tid; i < 1024; i += 512) ((int*)hA[0])[i] = 0;

    // ---- stage x(0)->xs[0], x(1)->xs[1] ----
    *(uint2*)&xs[0][ksx][xwbase] = pack4(xr0);
    *(uint2*)&xs[1][ksx][xwbase] = pack4(xr1);
    __syncthreads();

    // ---- xacc(0) from xs[0] ----
    f32x4 xacc[3];
    {
        bf16x8 xh0 = *(const bf16x8*)&xs[0][0][l * 8];
        xacc[0] = MFMA16(xh0, WI[0][0], cR4);
        xacc[1] = MFMA16(xh0, WI[1][0], cZ4);
        xacc[2] = MFMA16(xh0, WI[2][0], cN4);
        #pragma unroll
        for (int ks = 1; ks < 4; ++ks) {
            bf16x8 xh = *(const bf16x8*)&xs[0][ks][l * 8];
            #pragma unroll
            for (int q = 0; q < 3; ++q)
                xacc[q] = MFMA16(xh, WI[q][ks], xacc[q]);
        }
    }
    // issue x(2)
    float4 xraw = *(const float4*)xptr;
    txs = (txs + 1 == LL) ? 0 : txs + 1;
    xptr = (txs == 0) ? xptr - xwrap : xptr + xstep;

    __syncthreads();   // protect xs[0] from step-0 overwrite

    // ---- step body: HB/HN compile-time -> static LDS offsets ----
#define STEP_BODY(HB, HN)                                                      \
    {                                                                          \
        f32x4 racc[3];                                                         \
        {                                                                      \
            bf16x8 ah0 = *(const bf16x8*)&hA[HB][0][l * 8];                    \
            racc[0] = MFMA16(ah0, BH[0][0], cZZ);                              \
            racc[1] = MFMA16(ah0, BH[1][0], cZZ);                              \
            racc[2] = MFMA16(ah0, BH[2][0], cHN4);                             \
            _Pragma("unroll")                                                  \
            for (int ks = 1; ks < 4; ++ks) {                                   \
                bf16x8 ah = *(const bf16x8*)&hA[HB][ks][l * 8];                \
                _Pragma("unroll")                                              \
                for (int q = 0; q < 3; ++q)                                    \
                    racc[q] = MFMA16(ah, BH[q][ks], racc[q]);                  \
            }                                                                  \
        }                                                                      \
        float hnew[4];                                                         \
        _Pragma("unroll")                                                      \
        for (int r = 0; r < 4; ++r) {                                          \
            float gr = sigm_(racc[0][r] + xacc[0][r]);                         \
            float gz = sigm_(racc[1][r] + xacc[1][r]);                         \
            float gn = tanhf_(xacc[2][r] + gr * racc[2][r]);                   \
            float hv = gn + gz * (hold[r] - gn);                               \
            hnew[r] = hv;                                                      \
            hold[r] = hv;                                                      \
        }                                                                      \
        {                                                                      \
            unsigned pk01 = cvtpk(hold[0], hold[1]);                           \
            unsigned pk23 = cvtpk(hold[2], hold[3]);                           \
            hA[HN][ksw][hwbase]      = (short)(pk01 & 0xffffu);                \
            hA[HN][ksw][hwbase + 8]  = (short)(pk01 >> 16);                    \
            hA[HN][ksw][hwbase + 16] = (short)(pk23 & 0xffffu);                \
            hA[HN][ksw][hwbase + 24] = (short)(pk23 >> 16);                    \
        }                                                                      \
        _Pragma("unroll")                                                      \
        for (int r = 0; r < 4; ++r) {                                          \
            int t = tcur[r];                                                   \
            *optr[r] = (t < lenr[r]) ? hnew[r] : 0.0f;                         \
            int wrapped = (t + 1 == LL);                                       \
            tcur[r] = wrapped ? 0 : t + 1;                                     \
            optr[r] = wrapped ? optr[r] - owrap : optr[r] + HH;                \
        }                                                                      \
        {                                                                      \
            bf16x8 xh0 = *(const bf16x8*)&xs[HN][0][l * 8];                    \
            xacc[0] = MFMA16(xh0, WI[0][0], cR4);                              \
            xacc[1] = MFMA16(xh0, WI[1][0], cZ4);                              \
            xacc[2] = MFMA16(xh0, WI[2][0], cN4);                              \
            _Pragma("unroll")                                                  \
            for (int ks = 1; ks < 4; ++ks) {                                   \
                bf16x8 xh = *(const bf16x8*)&xs[HN][ks][l * 8];                \
                _Pragma("unroll")                                              \
                for (int q = 0; q < 3; ++q)                                    \
                    xacc[q] = MFMA16(xh, WI[q][ks], xacc[q]);                  \
            }                                                                  \
        }                                                                      \
        *(uint2*)&xs[HB][ksx][xwbase] = pack4(xraw);                           \
        xraw = *(const float4*)xptr;                                           \
        txs = (txs + 1 == LL) ? 0 : txs + 1;                                   \
        xptr = (txs == 0) ? xptr - xwrap : xptr + xstep;                       \
        asm volatile("s_waitcnt lgkmcnt(0)" ::: "memory");                     \
        __builtin_amdgcn_s_barrier();                                          \
        __builtin_amdgcn_sched_barrier(0);                                     \
    }

    // =======================  main loop (100 x 2 steps)  =======================
    for (int si2 = 0; si2 < LL; si2 += 2) {
        STEP_BODY(0, 1)
        STEP_BODY(1, 0)
    }
#undef STEP_BODY
}

extern "C" void kernel_launch(void* const* d_in, const int* in_sizes, int n_in,
                              void* d_out, int out_size, void* d_ws, size_t ws_size,
                              hipStream_t stream) {
    const float* seqs  = (const float*)d_in[0];
    const unsigned char* tmask = (const unsigned char*)d_in[1];
    // d_in[2] = attention_mask (all false, unused)
    const float* W_ih  = (const float*)d_in[3];
    const float* W_hh  = (const float*)d_in[4];
    const float* b_ih  = (const float*)d_in[5];
    const float* b_hh  = (const float*)d_in[6];
    float* out = (float*)d_out;

    char* ws = (char*)d_ws;
    int*   lens   = (int*)(ws);                       // 1 KB
    short* wih_hi = (short*)(ws + 1024);              // 384 KB
    short* whh_hi = (short*)(ws + 1024 + 393216);     // 384 KB

    compute_lens_kernel<<<1, BB, 0, stream>>>(tmask, lens);
    wsplit_kernel<<<768, 256, 0, stream>>>(W_ih, W_hh, wih_hi, whh_hi);

    gru_fused_kernel<<<dim3(16, CC), 512, 0, stream>>>(
        seqs, lens, wih_hi, whh_hi, b_ih, b_hh, out);
}

// Round 21
// 179.828 us; speedup vs baseline: 1.5583x; 1.1270x over previous
//
#include <hip/hip_runtime.h>
#include <hip/hip_bf16.h>

#define BB 256
#define LL 200
#define CC 4
#define HH 128
#define G3 384
#define XP 136   // row stride (shorts): 272B = 17*16B aligned; bank shift 4/row -> 2-way (free)

typedef short bf16x8 __attribute__((ext_vector_type(8)));
typedef float f32x4 __attribute__((ext_vector_type(4)));

#define MFMA16(a, b, c) __builtin_amdgcn_mfma_f32_16x16x32_bf16((a), (b), (c), 0, 0, 0)

__device__ __forceinline__ short bf16_rne(float x) {
    union { float f; unsigned u; } v; v.f = x;
    unsigned r = v.u + 0x7FFFu + ((v.u >> 16) & 1u);
    return (short)(r >> 16);
}
__device__ __forceinline__ float rcp_(float x) { return __builtin_amdgcn_rcpf(x); }
__device__ __forceinline__ float sigm_(float x) { return rcp_(1.0f + __expf(-x)); }
__device__ __forceinline__ float tanhf_(float x) { return 2.0f * rcp_(1.0f + __expf(-2.0f * x)) - 1.0f; }

__device__ __forceinline__ unsigned cvtpk(float lo, float hi) {
    unsigned r;
    asm("v_cvt_pk_bf16_f32 %0, %1, %2" : "=v"(r) : "v"(lo), "v"(hi));
    return r;
}
__device__ __forceinline__ uint2 pack4(float4 v) {
    uint2 p;
    p.x = cvtpk(v.x, v.y);
    p.y = cvtpk(v.z, v.w);
    return p;
}

// ---------------------------------------------------------------------------
// lengths from timeline_mask (bool-dtype detection, verified R1-R20)
// ---------------------------------------------------------------------------
__global__ void compute_lens_kernel(const unsigned char* __restrict__ mask8,
                                    int* __restrict__ lens) {
    __shared__ int bad;
    int b = threadIdx.x;
    if (b == 0) bad = 0;
    __syncthreads();
    int cnt8 = 0, prev = 0, mono = 1;
    for (int t = 0; t < LL; ++t) {
        int v = mask8[b * LL + t] ? 1 : 0;
        cnt8 += (v == 0);
        if (v < prev) mono = 0;
        prev = v;
    }
    if (!mono) atomicAdd(&bad, 1);
    __syncthreads();
    int len;
    if (bad == 0) {
        len = cnt8;
    } else {
        const int* m32 = (const int*)mask8;
        int c = 0;
        for (int t = 0; t < LL; ++t) c += (m32[b * LL + t] == 0);
        len = c;
    }
    if (len < 1) len = 1;
    if (len > LL) len = LL;
    lens[b] = len;
}

// ---------------------------------------------------------------------------
// weight split: bf16 hi for W_ih and W_hh
// ---------------------------------------------------------------------------
__global__ void wsplit_kernel(const float* __restrict__ Wih, const float* __restrict__ Whh,
                              short* __restrict__ wih_hi, short* __restrict__ whh_hi) {
    int i = blockIdx.x * 256 + threadIdx.x;   // 768 blocks -> 196608
    wih_hi[i] = bf16_rne(Wih[i]);
    whh_hi[i] = bf16_rne(Whh[i]);
}

// ---------------------------------------------------------------------------
// Fused GRU: grid (16 bt x 4 c) = 64 WGs, 512 thr = 8 waves = 2 waves/SIMD.
// R21 = R20 with MFMA OPERANDS SWAPPED: D = W.h^T (A=weights, B=h/x).
//   D col=lane&15 = BATCH, row = gate-dim -> lane holds 4 CONSECUTIVE dims
//   of 1 batch. Consequences:
//   - h-write: one contiguous ds_write_b64/lane (was 4 scattered b16)
//   - hA/xs: plain row-major [16][XP=136] (2-way = free), reads still b128
//   - out: ONE global_store_dwordx4/lane (was 4 dword stores), 1 pointer
//   - stager writes row-major (no frag-scatter math)
//   - weight frag loads + MFMA count unchanged (A/B lane layouts symmetric)
// Same arithmetic -> absmax ~0.005859375. Unroll-by-2 + lgkm-only barrier
// lineage kept.
// ---------------------------------------------------------------------------
__global__ __launch_bounds__(512, 2) void gru_fused_kernel(
    const float* __restrict__ seqs,    // (B,L,C,H)
    const int*   __restrict__ lens,    // (B,)
    const short* __restrict__ wih_hi,  // (C,384,128) bf16
    const short* __restrict__ whh_hi,  // (C,384,128) bf16
    const float* __restrict__ b_ih,    // (C,384)
    const float* __restrict__ b_hh,    // (C,384)
    float*       __restrict__ out)     // (C,B,L,H)
{
    const int bt = blockIdx.x;             // 0..15
    const int c  = blockIdx.y;             // 0..3
    const int bbase = bt * 16;
    const int tid = threadIdx.x;           // 0..511
    const int w = tid >> 6;                // wave 0..7
    const int l = tid & 63;
    const int l15 = l & 15, g = l >> 4;    // l15 = BATCH, g = k-group / reg-quad

    // row-major: [buf][batch][k], XP-short stride
    __shared__ __align__(16) short hA[2][16][XP];
    __shared__ __align__(16) short xs[2][16][XP];

    // ---- weight A-fragments: tile NT rows NT*16+l15, k = ks*32+g*8+j ----
    // NT(q) = q*8 + w: wave w owns gate-dims [16w,16w+16) of each gate
    bf16x8 BH[3][4], WI[3][4];
    #pragma unroll
    for (int q = 0; q < 3; ++q) {
        const int NT = q * 8 + w;
        #pragma unroll
        for (int ks = 0; ks < 4; ++ks) {
            size_t off = (size_t)(c * G3 + NT * 16 + l15) * HH + ks * 32 + g * 8;
            BH[q][ks] = *(const bf16x8*)(whh_hi + off);
            WI[q][ks] = *(const bf16x8*)(wih_hi + off);
        }
    }

    // ---- per-lane dims: dim0 = w*16 + g*4 (4 consecutive) ----
    const int dim0 = w * 16 + g * 4;

    // ---- biases -> per-r C-init vectors (float4 loads, 16B aligned) ----
    f32x4 cR4, cZ4, cHN4, cN4;
    {
        float4 rh = *(const float4*)(b_hh + c * G3 + dim0);
        float4 ri = *(const float4*)(b_ih + c * G3 + dim0);
        float4 zh = *(const float4*)(b_hh + c * G3 + 128 + dim0);
        float4 zi = *(const float4*)(b_ih + c * G3 + 128 + dim0);
        float4 nh = *(const float4*)(b_hh + c * G3 + 256 + dim0);
        float4 ni = *(const float4*)(b_ih + c * G3 + 256 + dim0);
        cR4  = (f32x4){rh.x + ri.x, rh.y + ri.y, rh.z + ri.z, rh.w + ri.w};
        cZ4  = (f32x4){zh.x + zi.x, zh.y + zi.y, zh.z + zi.z, zh.w + zi.w};
        cHN4 = (f32x4){nh.x, nh.y, nh.z, nh.w};
        cN4  = (f32x4){ni.x, ni.y, ni.z, ni.w};
    }
    const f32x4 cZZ = (f32x4){0.f, 0.f, 0.f, 0.f};

    // ---- per-lane output state: ONE batch (l15), 4 dims ----
    const int bme = bbase + l15;
    const int lenb = lens[bme];
    int tcur = LL - lenb;
    float* optr = out + ((size_t)(c * BB + bme) * LL + tcur) * HH + dim0;
    const ptrdiff_t owrap = (ptrdiff_t)(LL - 1) * HH;
    float hold[4] = { 0.f, 0.f, 0.f, 0.f };

    // ---- stager: thread stages batch row tid>>5, 4 floats at k0s ----
    const int bsl = tid >> 5;               // 0..15
    const int k0s = (tid & 31) * 4;         // 0..124
    const int lenS = lens[bbase + bsl];
    const float* srow0 = seqs + ((size_t)(bbase + bsl) * LL * CC + c) * HH + k0s;
    int ts0 = LL - lenS;
    int ts1 = ts0 + 1; if (ts1 >= LL) ts1 -= LL;
    float4 xr0 = *(const float4*)(srow0 + (size_t)ts0 * (CC * HH));
    float4 xr1 = *(const float4*)(srow0 + (size_t)ts1 * (CC * HH));
    int txs = ts1 + 1; if (txs >= LL) txs -= LL;   // t for s=2
    const float* xptr = srow0 + (size_t)txs * (CC * HH);
    const ptrdiff_t xstep = CC * HH;
    const ptrdiff_t xwrap = (ptrdiff_t)(LL - 1) * CC * HH;

    // ---- zero h buffer 0 (16*XP shorts = 1088 dwords) ----
    for (int i = tid; i < 16 * XP / 2; i += 512) ((int*)hA[0])[i] = 0;

    // ---- stage x(0)->xs[0], x(1)->xs[1] (row-major) ----
    *(uint2*)&xs[0][bsl][k0s] = pack4(xr0);
    *(uint2*)&xs[1][bsl][k0s] = pack4(xr1);
    __syncthreads();

    // ---- xacc(0) from xs[0]: B-frag = xs[l15][ks*32+g*8..] ----
    f32x4 xacc[3];
    {
        bf16x8 xb0 = *(const bf16x8*)&xs[0][l15][g * 8];
        xacc[0] = MFMA16(WI[0][0], xb0, cR4);
        xacc[1] = MFMA16(WI[1][0], xb0, cZ4);
        xacc[2] = MFMA16(WI[2][0], xb0, cN4);
        #pragma unroll
        for (int ks = 1; ks < 4; ++ks) {
            bf16x8 xb = *(const bf16x8*)&xs[0][l15][ks * 32 + g * 8];
            #pragma unroll
            for (int q = 0; q < 3; ++q)
                xacc[q] = MFMA16(WI[q][ks], xb, xacc[q]);
        }
    }
    // issue x(2)
    float4 xraw = *(const float4*)xptr;
    txs = (txs + 1 == LL) ? 0 : txs + 1;
    xptr = (txs == 0) ? xptr - xwrap : xptr + xstep;

    __syncthreads();   // protect xs[0] from step-0 overwrite

    // ---- step body: HB/HN compile-time ----
#define STEP_BODY(HB, HN)                                                      \
    {                                                                          \
        f32x4 racc[3];                                                         \
        {                                                                      \
            bf16x8 hb0 = *(const bf16x8*)&hA[HB][l15][g * 8];                  \
            racc[0] = MFMA16(BH[0][0], hb0, cZZ);                              \
            racc[1] = MFMA16(BH[1][0], hb0, cZZ);                              \
            racc[2] = MFMA16(BH[2][0], hb0, cHN4);                             \
            _Pragma("unroll")                                                  \
            for (int ks = 1; ks < 4; ++ks) {                                   \
                bf16x8 hbf = *(const bf16x8*)&hA[HB][l15][ks * 32 + g * 8];    \
                _Pragma("unroll")                                              \
                for (int q = 0; q < 3; ++q)                                    \
                    racc[q] = MFMA16(BH[q][ks], hbf, racc[q]);                 \
            }                                                                  \
        }                                                                      \
        float hnew[4];                                                         \
        _Pragma("unroll")                                                      \
        for (int r = 0; r < 4; ++r) {                                          \
            float gr = sigm_(racc[0][r] + xacc[0][r]);                         \
            float gz = sigm_(racc[1][r] + xacc[1][r]);                         \
            float gn = tanhf_(xacc[2][r] + gr * racc[2][r]);                   \
            float hv = gn + gz * (hold[r] - gn);                               \
            hnew[r] = hv;                                                      \
            hold[r] = hv;                                                      \
        }                                                                      \
        {                                                                      \
            uint2 pk;                                                          \
            pk.x = cvtpk(hold[0], hold[1]);                                    \
            pk.y = cvtpk(hold[2], hold[3]);                                    \
            *(uint2*)&hA[HN][l15][dim0] = pk;   /* one b64, 2-way free */      \
        }                                                                      \
        {                                                                      \
            int valid = tcur < lenb;                                           \
            float4 ov;                                                         \
            ov.x = valid ? hnew[0] : 0.0f;                                     \
            ov.y = valid ? hnew[1] : 0.0f;                                     \
            ov.z = valid ? hnew[2] : 0.0f;                                     \
            ov.w = valid ? hnew[3] : 0.0f;                                     \
            *(float4*)optr = ov;                /* one dwordx4 */              \
            int wrapped = (tcur + 1 == LL);                                    \
            tcur = wrapped ? 0 : tcur + 1;                                     \
            optr = wrapped ? optr - owrap : optr + HH;                         \
        }                                                                      \
        {                                                                      \
            bf16x8 xb0 = *(const bf16x8*)&xs[HN][l15][g * 8];                  \
            xacc[0] = MFMA16(WI[0][0], xb0, cR4);                              \
            xacc[1] = MFMA16(WI[1][0], xb0, cZ4);                              \
            xacc[2] = MFMA16(WI[2][0], xb0, cN4);                              \
            _Pragma("unroll")                                                  \
            for (int ks = 1; ks < 4; ++ks) {                                   \
                bf16x8 xb = *(const bf16x8*)&xs[HN][l15][ks * 32 + g * 8];     \
                _Pragma("unroll")                                              \
                for (int q = 0; q < 3; ++q)                                    \
                    xacc[q] = MFMA16(WI[q][ks], xb, xacc[q]);                  \
            }                                                                  \
        }                                                                      \
        *(uint2*)&xs[HB][bsl][k0s] = pack4(xraw);                              \
        xraw = *(const float4*)xptr;                                           \
        txs = (txs + 1 == LL) ? 0 : txs + 1;                                   \
        xptr = (txs == 0) ? xptr - xwrap : xptr + xstep;                       \
        asm volatile("s_waitcnt lgkmcnt(0)" ::: "memory");                     \
        __builtin_amdgcn_s_barrier();                                          \
        __builtin_amdgcn_sched_barrier(0);                                     \
    }

    // =======================  main loop (100 x 2 steps)  =======================
    for (int si2 = 0; si2 < LL; si2 += 2) {
        STEP_BODY(0, 1)
        STEP_BODY(1, 0)
    }
#undef STEP_BODY
}

extern "C" void kernel_launch(void* const* d_in, const int* in_sizes, int n_in,
                              void* d_out, int out_size, void* d_ws, size_t ws_size,
                              hipStream_t stream) {
    const float* seqs  = (const float*)d_in[0];
    const unsigned char* tmask = (const unsigned char*)d_in[1];
    // d_in[2] = attention_mask (all false, unused)
    const float* W_ih  = (const float*)d_in[3];
    const float* W_hh  = (const float*)d_in[4];
    const float* b_ih  = (const float*)d_in[5];
    const float* b_hh  = (const float*)d_in[6];
    float* out = (float*)d_out;

    char* ws = (char*)d_ws;
    int*   lens   = (int*)(ws);                       // 1 KB
    short* wih_hi = (short*)(ws + 1024);              // 384 KB
    short* whh_hi = (short*)(ws + 1024 + 393216);     // 384 KB

    compute_lens_kernel<<<1, BB, 0, stream>>>(tmask, lens);
    wsplit_kernel<<<768, 256, 0, stream>>>(W_ih, W_hh, wih_hi, whh_hi);

    gru_fused_kernel<<<dim3(16, CC), 512, 0, stream>>>(
        seqs, lens, wih_hi, whh_hi, b_ih, b_hh, out);
}